// Round 5
// baseline (557.344 us; speedup 1.0000x reference)
//
#include <hip/hip_runtime.h>
#include <float.h>

// Disable FP contraction file-wide: IoU/encode/threshold compares must match
// numpy bit patterns; none of the hot loops are FMA-throughput-bound.
#pragma clang fp contract(off)

typedef unsigned long long ull;
typedef unsigned int u32;

#define THRESH 0.5f
#define PPT 4          // priors per thread in k_match
#define CE_R 128       // rows per block in k_fused
#define SEL_T 512      // threads in k_select

// ---------------------------------------------------------------- helpers

__device__ __forceinline__ float sl1(float d) {
    float a = fabsf(d);
    return (a < 1.f) ? 0.5f * d * d : a - 0.5f;
}

// ---------------------------------------------------------------- K1: match (both directions)
// Per-prior best truth: register-tiled, each thread owns PPT priors, strict >
// == jnp.argmax first-occurrence (smallest o).
// Per-truth best prior fused in: per-o register argmax over the thread's PPT
// priors -> packed key (iou_bits<<32)|~p -> LDS atomicMax w/ monotone
// prefilter -> one global atomicMax per (block,truth). Key order: larger iou
// wins; tie -> larger ~p == smaller p == first occurrence. All-zero IoU row
// decodes to p=0 (matches jnp.argmax(zeros)=0). Invalid (p>=P) lanes produce
// iou=0 keys with larger p -> lose to any valid key.
__global__ __launch_bounds__(256) void k_match(
        const float* __restrict__ targets, const float* __restrict__ priors,
        float* __restrict__ bto, int* __restrict__ bti,
        ull* __restrict__ tbest, int P, int O, int SEG) {
    const int b = blockIdx.y, seg = blockIdx.x;
    __shared__ float4 tbox[64];
    __shared__ float tarea[64];
    __shared__ ull bestL[64];
    const float* trow = targets + (size_t)b * O * 5;
    for (int o = threadIdx.x; o < O; o += blockDim.x) {
        float x1 = trow[o * 5 + 0], y1 = trow[o * 5 + 1];
        float x2 = trow[o * 5 + 2], y2 = trow[o * 5 + 3];
        tbox[o] = make_float4(x1, y1, x2, y2);
        tarea[o] = (x2 - x1) * (y2 - y1);
        bestL[o] = 0ull;
    }
    __syncthreads();
    const int p0 = seg * SEG;
    float px1[PPT], py1[PPT], px2[PPT], py2[PPT], pa[PPT];
    float bestv[PPT]; int besto[PPT]; int pidx[PPT];
#pragma unroll
    for (int j = 0; j < PPT; j++) {
        int p = p0 + (int)threadIdx.x + j * 256;
        pidx[j] = p; bestv[j] = -1.f; besto[j] = 0;
        if (p < P) {
            float4 pr = ((const float4*)priors)[p];
            px1[j] = pr.x - pr.z / 2.f;
            py1[j] = pr.y - pr.w / 2.f;
            px2[j] = pr.x + pr.z / 2.f;
            py2[j] = pr.y + pr.w / 2.f;
            pa[j] = (px2[j] - px1[j]) * (py2[j] - py1[j]);
        } else {
            px1[j] = 2.f; py1[j] = 2.f; px2[j] = 2.f; py2[j] = 2.f; pa[j] = 1.f;
        }
    }
    for (int o = 0; o < O; o++) {
        float4 t = tbox[o];
        float ta = tarea[o];
        float vmax = -1.f; int pmax = 0;
#pragma unroll
        for (int j = 0; j < PPT; j++) {
            float lx = fmaxf(t.x, px1[j]), ly = fmaxf(t.y, py1[j]);
            float rx = fminf(t.z, px2[j]), ry = fminf(t.w, py2[j]);
            float wx = fmaxf(rx - lx, 0.f), wy = fmaxf(ry - ly, 0.f);
            float inter = wx * wy;
            float iou = 0.f;
            if (inter > 0.f) iou = inter / (ta + pa[j] - inter);
            if (iou > bestv[j]) { bestv[j] = iou; besto[j] = o; }
            if (iou > vmax) { vmax = iou; pmax = pidx[j]; } // ascending pidx -> first max
        }
        ull key = ((ull)__float_as_uint(vmax) << 32) | (u32)(~(u32)pmax);
        ull cur = bestL[o];                 // monotone prefilter (racy read OK)
        if (key > cur) atomicMax(&bestL[o], key);
    }
    __syncthreads();
#pragma unroll
    for (int j = 0; j < PPT; j++) {
        if (pidx[j] < P) {
            bto[(size_t)b * P + pidx[j]] = bestv[j];
            bti[(size_t)b * P + pidx[j]] = besto[j];
        }
    }
    for (int o = threadIdx.x; o < O; o += blockDim.x)
        atomicMax(&tbest[(size_t)b * O + o], bestL[o]);
}

// ---------------------------------------------------------------- K2: fused force+encode+CE+key
// Block = CE_R contiguous (b,p) rows. Stages conf rows to LDS (float4), builds
// the forcing-override window from tbest (numpy last-wins == max-o atomicMax),
// computes conf_t, smooth-L1 loc loss, logsumexp CE (2 threads/row), and emits
// the selection key (pos -> 0, neg -> ce bits) in place of bti. Per-batch
// (num_pos, loss_l, pos-ce-sum) accumulated via <=2 batch passes (a block
// spans at most 2 batches since CE_R < P).
__global__ __launch_bounds__(256) void k_fused(
        const float* __restrict__ conf, const float* __restrict__ targets,
        const float* __restrict__ priors, const float* __restrict__ loc_data,
        const ull* __restrict__ tbest, const float* __restrict__ bto,
        int* bti_keys,                       // read bti, write keys (aliased!)
        int* __restrict__ num_pos, float* __restrict__ loss_l,
        float* __restrict__ lcpos, int P, int O, long long BP) {
    __shared__ float s[CE_R * 81];
    __shared__ float tr[2][64 * 5];
    __shared__ int ov[CE_R];
    __shared__ float redf[4]; __shared__ int redi[4]; __shared__ float redp[4];
    const long long r0 = (long long)blockIdx.x * CE_R;
    const int nrow = (int)min((long long)CE_R, BP - r0);

    // stage conf rows (16B-aligned: r0*81*4 = blk*41472)
    int nfl = nrow * 81;
    const float* src = conf + r0 * 81;
    int nv4 = nfl >> 2;
    for (int i = threadIdx.x; i < nv4; i += 256)
        ((float4*)s)[i] = ((const float4*)src)[i];
    for (int i = (nv4 << 2) + (int)threadIdx.x; i < nfl; i += 256)
        s[i] = src[i];

    const int b0 = (int)(r0 / P);
    const int b1 = (int)((r0 + nrow - 1) / P);
    const int nb = (b1 != b0) ? 2 : 1;
    for (int i = threadIdx.x; i < O * 5; i += 256)
        tr[0][i] = targets[(size_t)b0 * O * 5 + i];
    if (nb == 2)
        for (int i = threadIdx.x; i < O * 5; i += 256)
            tr[1][i] = targets[(size_t)b1 * O * 5 + i];
    if ((int)threadIdx.x < CE_R) ov[threadIdx.x] = -1;
    __syncthreads();

    // forcing overrides within this row window
    for (int i = threadIdx.x; i < nb * O; i += 256) {
        int which = i / O, o = i - which * O;
        int bx = which ? b1 : b0;
        ull tb = tbest[(size_t)bx * O + o];
        u32 p = ~(u32)(tb & 0xFFFFFFFFull);
        if (p >= (u32)P) p = 0;
        long long r = (long long)bx * P + p;
        if (r >= r0 && r < r0 + nrow) atomicMax(&ov[(int)(r - r0)], o);
    }
    __syncthreads();

    const int row = threadIdx.x >> 1;
    const int half = threadIdx.x & 1;
    float ll = 0.f, ps = 0.f; int cnt = 0, myb = -1;
    if (row < nrow) {
        const float* rp = s + row * 81;
        int c0 = half * 41;
        int cn = half ? 40 : 41;
        float sum = 0.f;
        for (int j = 0; j < cn; j++) sum += __expf(rp[c0 + j]);
        sum += __shfl_xor(sum, 1);
        if (half == 0) {
            long long r = r0 + row;
            int b = (int)(r / P); myb = b;
            int p = (int)(r - (long long)b * P);
            const float* trb = tr[(b == b0) ? 0 : 1];
            int o = bti_keys[r];
            int ovv = ov[row];
            bool forced = ovv >= 0;
            if (forced) o = ovv;
            float ovl = bto[r];
            int cf = (!forced && ovl < THRESH) ? 0 : ((int)trb[o * 5 + 4] + 1);
            float ce = __logf(sum) - rp[cf];
            u32 key;
            if (cf > 0) {
                cnt = 1; ps = ce; key = 0u;
                float4 pr = ((const float4*)priors)[p];
                float mx1 = trb[o * 5], my1 = trb[o * 5 + 1];
                float mx2 = trb[o * 5 + 2], my2 = trb[o * 5 + 3];
                float gx = ((mx1 + mx2) / 2.f - pr.x) / (0.1f * pr.z);
                float gy = ((my1 + my2) / 2.f - pr.y) / (0.1f * pr.w);
                float gw = logf((mx2 - mx1) / pr.z) / 0.2f;
                float gh = logf((my2 - my1) / pr.w) / 0.2f;
                float4 ld = ((const float4*)loc_data)[r];
                ll = sl1(ld.x - gx) + sl1(ld.y - gy) + sl1(ld.z - gw) + sl1(ld.w - gh);
            } else {
                key = __float_as_uint(fmaxf(ce, 0.f));
            }
            ((u32*)bti_keys)[r] = key;
        }
    }
    // per-batch block reduction (<=2 batches)
    const int w = threadIdx.x >> 6;
    for (int pass = 0; pass < nb; pass++) {
        int bx = pass ? b1 : b0;
        float llv = (myb == bx) ? ll : 0.f;
        float pv  = (myb == bx) ? ps : 0.f;
        int   cv  = (myb == bx) ? cnt : 0;
        for (int off = 32; off; off >>= 1) {
            llv += __shfl_down(llv, off);
            pv  += __shfl_down(pv, off);
            cv  += __shfl_down(cv, off);
        }
        if ((threadIdx.x & 63) == 0) { redf[w] = llv; redp[w] = pv; redi[w] = cv; }
        __syncthreads();
        if (threadIdx.x == 0) {
            float l = 0.f, q = 0.f; int c = 0;
            for (int i = 0; i < 4; i++) { l += redf[i]; q += redp[i]; c += redi[i]; }
            if (c) {
                atomicAdd(&num_pos[bx], c);
                atomicAdd(&loss_l[bx], l);
                atomicAdd(&lcpos[bx], q);
            }
        }
        __syncthreads();
    }
}

// ---------------------------------------------------------------- K3: radix top-k select + final
// Keys in LDS. Per-pass 16-bin histogram via packed per-thread byte counters
// (2 x u64, 8-bit fields, <=18 elems/pass) + 16-bit-field butterfly reduce.
// Sum of top-k = sum(keys>t) + (k-count_gt)*t — exact under any tie order
// (== double-argsort selection sum). Last block (device-scope ticket) writes
// the final normalized outputs.
__global__ __launch_bounds__(SEL_T) void k_select(
        const u32* __restrict__ keys, const int* __restrict__ num_pos,
        const float* __restrict__ loss_l, const float* __restrict__ lcpos,
        float* __restrict__ acc, u32* __restrict__ ticket,
        float* __restrict__ out, int P, int B) {
    extern __shared__ u32 sk[];
    __shared__ u32 whist[SEL_T / 64][16];
    __shared__ u32 hist[16];
    __shared__ float redf[SEL_T / 64]; __shared__ u32 redu[SEL_T / 64];
    __shared__ u32 sh_pval; __shared__ int sh_rem;
    const int b = blockIdx.x;
    const size_t base = (size_t)b * P;
    const int lane = threadIdx.x & 63;
    const int w = threadIdx.x >> 6;
    const int NW = SEL_T / 64;

    for (int p = threadIdx.x; p < P; p += SEL_T) sk[p] = keys[base + p];

    const int np = num_pos[b];
    const int k = min(3 * np, P - 1);
    u32 pval = 0, pmask = 0; int rem = k;
    if (k > 0) {
        for (int shift = 28; shift >= 0; shift -= 4) {
            __syncthreads();
            ull a0 = 0, a1 = 0;
            for (int p = threadIdx.x; p < P; p += SEL_T) {
                u32 key = sk[p];
                if ((key & pmask) == pval) {
                    u32 dig = (key >> shift) & 15u;
                    ull inc = 1ull << ((dig & 7u) * 8u);
                    if (dig < 8u) a0 += inc; else a1 += inc;
                }
            }
            const ull M = 0x00FF00FF00FF00FFull;
            ull e0 = a0 & M, e1 = (a0 >> 8) & M, e2 = a1 & M, e3 = (a1 >> 8) & M;
            for (int off = 32; off; off >>= 1) {
                e0 += __shfl_xor(e0, off);
                e1 += __shfl_xor(e1, off);
                e2 += __shfl_xor(e2, off);
                e3 += __shfl_xor(e3, off);
            }
            if (lane == 0) {
#pragma unroll
                for (int j = 0; j < 4; j++) {
                    whist[w][2 * j]         = (u32)((e0 >> (16 * j)) & 0xFFFF);
                    whist[w][2 * j + 1]     = (u32)((e1 >> (16 * j)) & 0xFFFF);
                    whist[w][8 + 2 * j]     = (u32)((e2 >> (16 * j)) & 0xFFFF);
                    whist[w][8 + 2 * j + 1] = (u32)((e3 >> (16 * j)) & 0xFFFF);
                }
            }
            __syncthreads();
            if (threadIdx.x < 16) {
                u32 h = 0;
                for (int i = 0; i < NW; i++) h += whist[i][threadIdx.x];
                hist[threadIdx.x] = h;
            }
            __syncthreads();
            if (threadIdx.x == 0) {
                u32 accu = 0; int d = 15;
                for (; d > 0; d--) {
                    u32 h = hist[d];
                    if (accu + h >= (u32)rem) break;
                    accu += h;
                }
                sh_pval = pval | ((u32)d << shift);
                sh_rem = rem - (int)accu;
            }
            __syncthreads();
            pval = sh_pval; rem = sh_rem; pmask |= (0xFu << shift);
        }
    }

    float sgt = 0.f; u32 cgt = 0;
    if (k > 0) {
        for (int p = threadIdx.x; p < P; p += SEL_T) {
            u32 key = sk[p];
            if (key > pval) { sgt += __uint_as_float(key); cgt++; }
        }
    }
    for (int off = 32; off; off >>= 1) {
        sgt += __shfl_down(sgt, off);
        cgt += __shfl_down(cgt, off);
    }
    __syncthreads();
    if (lane == 0) { redf[w] = sgt; redu[w] = cgt; }
    __syncthreads();
    if (threadIdx.x == 0) {
        float s = 0.f; u32 c = 0;
        for (int i = 0; i < NW; i++) { s += redf[i]; c += redu[i]; }
        float t = __uint_as_float(pval);
        float lc_b = lcpos[b] + ((k > 0) ? (s + (float)(k - (int)c) * t) : 0.f);
        atomicAdd(&acc[0], (float)np);
        atomicAdd(&acc[1], loss_l[b]);
        atomicAdd(&acc[2], lc_b);
        __threadfence();
        u32 tk = atomicAdd(ticket, 1u);
        if (tk == (u32)(B - 1)) {
            float n  = atomicAdd(&acc[0], 0.f);   // coherent device-scope reads
            float ll = atomicAdd(&acc[1], 0.f);
            float lc = atomicAdd(&acc[2], 0.f);
            out[0] = ll / n;
            out[1] = lc / n;
        }
    }
}

// ---------------------------------------------------------------- launch

extern "C" void kernel_launch(void* const* d_in, const int* in_sizes, int n_in,
                              void* d_out, int out_size, void* d_ws, size_t ws_size,
                              hipStream_t stream) {
    const float* loc     = (const float*)d_in[0];
    const float* conf    = (const float*)d_in[1];
    const float* targets = (const float*)d_in[2];
    const float* priors  = (const float*)d_in[3];

    const int P = in_sizes[3] / 4;
    const int B = in_sizes[0] / (P * 4);
    const int O = in_sizes[2] / (B * 5);

    char* ws = (char*)d_ws;
    size_t off = 0;
    ull*   tbest   = (ull*)(ws + off);   off += (size_t)B * O * sizeof(ull);
    int*   num_pos = (int*)(ws + off);   off += (size_t)B * sizeof(int);
    float* loss_l  = (float*)(ws + off); off += (size_t)B * sizeof(float);
    float* lcpos   = (float*)(ws + off); off += (size_t)B * sizeof(float);
    float* acc     = (float*)(ws + off); off += 4 * sizeof(float);
    u32*   ticket  = (u32*)(ws + off);   off += sizeof(u32);
    const size_t zbytes = off;           // zero-init region
    off = (off + 15) & ~(size_t)15;
    float* F       = (float*)(ws + off); off += (size_t)B * P * sizeof(float); // bto
    int*   I       = (int*)(ws + off);   off += (size_t)B * P * sizeof(int);   // bti -> keys

    (void)hipMemsetAsync(d_ws, 0, zbytes, stream);

    const int SEG = 256 * PPT;
    const int S = (P + SEG - 1) / SEG;
    k_match<<<dim3(S, B), 256, 0, stream>>>(targets, priors, F, I, tbest, P, O, SEG);

    const long long BP = (long long)B * P;
    k_fused<<<(int)((BP + CE_R - 1) / CE_R), 256, 0, stream>>>(
        conf, targets, priors, loc, tbest, F, I, num_pos, loss_l, lcpos, P, O, BP);

    k_select<<<B, SEL_T, (size_t)P * sizeof(u32), stream>>>(
        (const u32*)I, num_pos, loss_l, lcpos, acc, ticket, (float*)d_out, P, B);
}

// Round 6
// 411.773 us; speedup vs baseline: 1.3535x; 1.3535x over previous
//
#include <hip/hip_runtime.h>
#include <float.h>

// Disable FP contraction file-wide: IoU/encode/threshold compares must match
// numpy bit patterns; none of the hot loops are FMA-throughput-bound.
#pragma clang fp contract(off)

typedef unsigned long long ull;
typedef unsigned int u32;

#define THRESH 0.5f
#define PPT 4          // priors per thread in k_match
#define CE_R 128       // rows per block in k_fused
#define SEL_T 512      // threads in k_select

// ---------------------------------------------------------------- helpers

__device__ __forceinline__ float sl1(float d) {
    float a = fabsf(d);
    return (a < 1.f) ? 0.5f * d * d : a - 0.5f;
}

// ---------------------------------------------------------------- K1: per-prior best truth
// Register-tiled: each thread owns PPT priors (corners inline), truths
// broadcast from LDS. No atomics (R5 lesson: same-address LDS atomicMax in
// the inner loop serializes 256-deep -> 24x slowdown). Strict > == jnp.argmax
// first-occurrence.
__global__ __launch_bounds__(256) void k_match(
        const float* __restrict__ targets, const float* __restrict__ priors,
        float* __restrict__ bto, int* __restrict__ bti, int P, int O, int SEG) {
    const int b = blockIdx.y, seg = blockIdx.x;
    __shared__ float4 tbox[64];
    __shared__ float tarea[64];
    const float* trow = targets + (size_t)b * O * 5;
    for (int o = threadIdx.x; o < O; o += blockDim.x) {
        float x1 = trow[o * 5 + 0], y1 = trow[o * 5 + 1];
        float x2 = trow[o * 5 + 2], y2 = trow[o * 5 + 3];
        tbox[o] = make_float4(x1, y1, x2, y2);
        tarea[o] = (x2 - x1) * (y2 - y1);
    }
    __syncthreads();
    const int p0 = seg * SEG;
    float px1[PPT], py1[PPT], px2[PPT], py2[PPT], pa[PPT];
    float bestv[PPT]; int besto[PPT]; int pidx[PPT];
#pragma unroll
    for (int j = 0; j < PPT; j++) {
        int p = p0 + (int)threadIdx.x + j * 256;
        pidx[j] = p; bestv[j] = -1.f; besto[j] = 0;
        if (p < P) {
            float4 pr = ((const float4*)priors)[p];
            px1[j] = pr.x - pr.z / 2.f;
            py1[j] = pr.y - pr.w / 2.f;
            px2[j] = pr.x + pr.z / 2.f;
            py2[j] = pr.y + pr.w / 2.f;
            pa[j] = (px2[j] - px1[j]) * (py2[j] - py1[j]);
        } else {
            px1[j] = 2.f; py1[j] = 2.f; px2[j] = 2.f; py2[j] = 2.f; pa[j] = 1.f;
        }
    }
    for (int o = 0; o < O; o++) {
        float4 t = tbox[o];
        float ta = tarea[o];
#pragma unroll
        for (int j = 0; j < PPT; j++) {
            float lx = fmaxf(t.x, px1[j]), ly = fmaxf(t.y, py1[j]);
            float rx = fminf(t.z, px2[j]), ry = fminf(t.w, py2[j]);
            float wx = fmaxf(rx - lx, 0.f), wy = fmaxf(ry - ly, 0.f);
            float inter = wx * wy;
            float iou = 0.f;
            if (inter > 0.f) iou = inter / (ta + pa[j] - inter);
            if (iou > bestv[j]) { bestv[j] = iou; besto[j] = o; }
        }
    }
#pragma unroll
    for (int j = 0; j < PPT; j++) {
        if (pidx[j] < P) {
            bto[(size_t)b * P + pidx[j]] = bestv[j];
            bti[(size_t)b * P + pidx[j]] = besto[j];
        }
    }
}

// ---------------------------------------------------------------- K1b: per-truth best prior
// One wave per 2 truths, scans all priors (corners inline). Packed key
// (iou_bits<<32)|~p: register max + shuffle butterfly, ZERO atomics; plain
// store -> tbest needs no zero-init. Larger iou wins; tie -> larger ~p ==
// smaller p == first occurrence. All-zero IoU row decodes to p=0
// (matches jnp.argmax(zeros)=0).
__global__ __launch_bounds__(256) void k_tbest(
        const float* __restrict__ targets, const float* __restrict__ priors,
        ull* __restrict__ tbest, int P, int O, int npairs) {
    int g = blockIdx.x * 4 + ((int)threadIdx.x >> 6);
    int lane = threadIdx.x & 63;
    if (g >= npairs) return;
    int OP = (O + 1) >> 1;
    int b = g / OP;
    int o0 = (g % OP) * 2;
    const float* trow = targets + ((size_t)b * O + o0) * 5;
    float ax1 = trow[0], ay1 = trow[1], ax2 = trow[2], ay2 = trow[3];
    float ta0 = (ax2 - ax1) * (ay2 - ay1);
    bool has1 = (o0 + 1) < O;
    float cx1 = 0, cy1 = 0, cx2 = 0, cy2 = 0, ta1 = 1.f;
    if (has1) {
        cx1 = trow[5]; cy1 = trow[6]; cx2 = trow[7]; cy2 = trow[8];
        ta1 = (cx2 - cx1) * (cy2 - cy1);
    }
    ull k0 = 0, k1 = 0;
    for (int p = lane; p < P; p += 64) {
        float4 pr = ((const float4*)priors)[p];
        float bx1 = pr.x - pr.z / 2.f;
        float by1 = pr.y - pr.w / 2.f;
        float bx2 = pr.x + pr.z / 2.f;
        float by2 = pr.y + pr.w / 2.f;
        float pa = (bx2 - bx1) * (by2 - by1);
        u32 np = ~(u32)p;
        {
            float lx = fmaxf(ax1, bx1), ly = fmaxf(ay1, by1);
            float rx = fminf(ax2, bx2), ry = fminf(ay2, by2);
            float wx = fmaxf(rx - lx, 0.f), wy = fmaxf(ry - ly, 0.f);
            float inter = wx * wy;
            float iou = 0.f;
            if (inter > 0.f) iou = inter / (ta0 + pa - inter);
            ull key = ((ull)__float_as_uint(iou) << 32) | np;
            if (key > k0) k0 = key;
        }
        if (has1) {
            float lx = fmaxf(cx1, bx1), ly = fmaxf(cy1, by1);
            float rx = fminf(cx2, bx2), ry = fminf(cy2, by2);
            float wx = fmaxf(rx - lx, 0.f), wy = fmaxf(ry - ly, 0.f);
            float inter = wx * wy;
            float iou = 0.f;
            if (inter > 0.f) iou = inter / (ta1 + pa - inter);
            ull key = ((ull)__float_as_uint(iou) << 32) | np;
            if (key > k1) k1 = key;
        }
    }
    for (int off = 32; off; off >>= 1) {
        ull a = __shfl_xor(k0, off); if (a > k0) k0 = a;
        ull d = __shfl_xor(k1, off); if (d > k1) k1 = d;
    }
    if (lane == 0) {
        tbest[(size_t)b * O + o0] = k0;
        if (has1) tbest[(size_t)b * O + o0 + 1] = k1;
    }
}

// ---------------------------------------------------------------- K2: fused force+encode+CE+key
// Block = CE_R contiguous (b,p) rows. Stages conf rows to LDS (float4), builds
// the forcing-override window from tbest (numpy last-wins == max-o atomicMax,
// <=100 LDS atomics across DISTINCT addresses -> no contention), computes
// conf_t, smooth-L1 loc loss, logsumexp CE (2 threads/row), and emits the
// selection key (pos -> 0, neg -> ce bits) in place of bti. Per-batch
// (num_pos, loss_l, pos-ce-sum) accumulated via <=2 batch passes.
__global__ __launch_bounds__(256) void k_fused(
        const float* __restrict__ conf, const float* __restrict__ targets,
        const float* __restrict__ priors, const float* __restrict__ loc_data,
        const ull* __restrict__ tbest, const float* __restrict__ bto,
        int* bti_keys,                       // read bti, write keys (aliased!)
        int* __restrict__ num_pos, float* __restrict__ loss_l,
        float* __restrict__ lcpos, int P, int O, long long BP) {
    __shared__ float s[CE_R * 81];
    __shared__ float tr[2][64 * 5];
    __shared__ int ov[CE_R];
    __shared__ float redf[4]; __shared__ int redi[4]; __shared__ float redp[4];
    const long long r0 = (long long)blockIdx.x * CE_R;
    const int nrow = (int)min((long long)CE_R, BP - r0);

    // stage conf rows (16B-aligned: r0*81*4 = blk*41472)
    int nfl = nrow * 81;
    const float* src = conf + r0 * 81;
    int nv4 = nfl >> 2;
    for (int i = threadIdx.x; i < nv4; i += 256)
        ((float4*)s)[i] = ((const float4*)src)[i];
    for (int i = (nv4 << 2) + (int)threadIdx.x; i < nfl; i += 256)
        s[i] = src[i];

    const int b0 = (int)(r0 / P);
    const int b1 = (int)((r0 + nrow - 1) / P);
    const int nb = (b1 != b0) ? 2 : 1;
    for (int i = threadIdx.x; i < O * 5; i += 256)
        tr[0][i] = targets[(size_t)b0 * O * 5 + i];
    if (nb == 2)
        for (int i = threadIdx.x; i < O * 5; i += 256)
            tr[1][i] = targets[(size_t)b1 * O * 5 + i];
    if ((int)threadIdx.x < CE_R) ov[threadIdx.x] = -1;
    __syncthreads();

    // forcing overrides within this row window
    for (int i = threadIdx.x; i < nb * O; i += 256) {
        int which = i / O, o = i - which * O;
        int bx = which ? b1 : b0;
        ull tb = tbest[(size_t)bx * O + o];
        u32 p = ~(u32)(tb & 0xFFFFFFFFull);
        if (p >= (u32)P) p = 0;
        long long r = (long long)bx * P + p;
        if (r >= r0 && r < r0 + nrow) atomicMax(&ov[(int)(r - r0)], o);
    }
    __syncthreads();

    const int row = threadIdx.x >> 1;
    const int half = threadIdx.x & 1;
    float ll = 0.f, ps = 0.f; int cnt = 0, myb = -1;
    if (row < nrow) {
        const float* rp = s + row * 81;
        int c0 = half * 41;
        int cn = half ? 40 : 41;
        float sum = 0.f;
        for (int j = 0; j < cn; j++) sum += __expf(rp[c0 + j]);
        sum += __shfl_xor(sum, 1);
        if (half == 0) {
            long long r = r0 + row;
            int b = (int)(r / P); myb = b;
            int p = (int)(r - (long long)b * P);
            const float* trb = tr[(b == b0) ? 0 : 1];
            int o = bti_keys[r];
            int ovv = ov[row];
            bool forced = ovv >= 0;
            if (forced) o = ovv;
            float ovl = bto[r];
            int cf = (!forced && ovl < THRESH) ? 0 : ((int)trb[o * 5 + 4] + 1);
            float ce = __logf(sum) - rp[cf];
            u32 key;
            if (cf > 0) {
                cnt = 1; ps = ce; key = 0u;
                float4 pr = ((const float4*)priors)[p];
                float mx1 = trb[o * 5], my1 = trb[o * 5 + 1];
                float mx2 = trb[o * 5 + 2], my2 = trb[o * 5 + 3];
                float gx = ((mx1 + mx2) / 2.f - pr.x) / (0.1f * pr.z);
                float gy = ((my1 + my2) / 2.f - pr.y) / (0.1f * pr.w);
                float gw = logf((mx2 - mx1) / pr.z) / 0.2f;
                float gh = logf((my2 - my1) / pr.w) / 0.2f;
                float4 ld = ((const float4*)loc_data)[r];
                ll = sl1(ld.x - gx) + sl1(ld.y - gy) + sl1(ld.z - gw) + sl1(ld.w - gh);
            } else {
                key = __float_as_uint(fmaxf(ce, 0.f));
            }
            ((u32*)bti_keys)[r] = key;
        }
    }
    // per-batch block reduction (<=2 batches)
    const int w = threadIdx.x >> 6;
    for (int pass = 0; pass < nb; pass++) {
        int bx = pass ? b1 : b0;
        float llv = (myb == bx) ? ll : 0.f;
        float pv  = (myb == bx) ? ps : 0.f;
        int   cv  = (myb == bx) ? cnt : 0;
        for (int off = 32; off; off >>= 1) {
            llv += __shfl_down(llv, off);
            pv  += __shfl_down(pv, off);
            cv  += __shfl_down(cv, off);
        }
        if ((threadIdx.x & 63) == 0) { redf[w] = llv; redp[w] = pv; redi[w] = cv; }
        __syncthreads();
        if (threadIdx.x == 0) {
            float l = 0.f, q = 0.f; int c = 0;
            for (int i = 0; i < 4; i++) { l += redf[i]; q += redp[i]; c += redi[i]; }
            if (c) {
                atomicAdd(&num_pos[bx], c);
                atomicAdd(&loss_l[bx], l);
                atomicAdd(&lcpos[bx], q);
            }
        }
        __syncthreads();
    }
}

// ---------------------------------------------------------------- K3: radix top-k select + final
// Keys in LDS. Per-pass 16-bin histogram via packed per-thread byte counters
// (2 x u64, 8-bit fields, <=18 elems/pass) + 16-bit-field butterfly reduce.
// Sum of top-k = sum(keys>t) + (k-count_gt)*t — exact under any tie order
// (== double-argsort selection sum). Last block (device-scope ticket) writes
// the final normalized outputs.
__global__ __launch_bounds__(SEL_T) void k_select(
        const u32* __restrict__ keys, const int* __restrict__ num_pos,
        const float* __restrict__ loss_l, const float* __restrict__ lcpos,
        float* __restrict__ acc, u32* __restrict__ ticket,
        float* __restrict__ out, int P, int B) {
    extern __shared__ u32 sk[];
    __shared__ u32 whist[SEL_T / 64][16];
    __shared__ u32 hist[16];
    __shared__ float redf[SEL_T / 64]; __shared__ u32 redu[SEL_T / 64];
    __shared__ u32 sh_pval; __shared__ int sh_rem;
    const int b = blockIdx.x;
    const size_t base = (size_t)b * P;
    const int lane = threadIdx.x & 63;
    const int w = threadIdx.x >> 6;
    const int NW = SEL_T / 64;

    for (int p = threadIdx.x; p < P; p += SEL_T) sk[p] = keys[base + p];

    const int np = num_pos[b];
    const int k = min(3 * np, P - 1);
    u32 pval = 0, pmask = 0; int rem = k;
    if (k > 0) {
        for (int shift = 28; shift >= 0; shift -= 4) {
            __syncthreads();
            ull a0 = 0, a1 = 0;
            for (int p = threadIdx.x; p < P; p += SEL_T) {
                u32 key = sk[p];
                if ((key & pmask) == pval) {
                    u32 dig = (key >> shift) & 15u;
                    ull inc = 1ull << ((dig & 7u) * 8u);
                    if (dig < 8u) a0 += inc; else a1 += inc;
                }
            }
            const ull M = 0x00FF00FF00FF00FFull;
            ull e0 = a0 & M, e1 = (a0 >> 8) & M, e2 = a1 & M, e3 = (a1 >> 8) & M;
            for (int off = 32; off; off >>= 1) {
                e0 += __shfl_xor(e0, off);
                e1 += __shfl_xor(e1, off);
                e2 += __shfl_xor(e2, off);
                e3 += __shfl_xor(e3, off);
            }
            if (lane == 0) {
#pragma unroll
                for (int j = 0; j < 4; j++) {
                    whist[w][2 * j]         = (u32)((e0 >> (16 * j)) & 0xFFFF);
                    whist[w][2 * j + 1]     = (u32)((e1 >> (16 * j)) & 0xFFFF);
                    whist[w][8 + 2 * j]     = (u32)((e2 >> (16 * j)) & 0xFFFF);
                    whist[w][8 + 2 * j + 1] = (u32)((e3 >> (16 * j)) & 0xFFFF);
                }
            }
            __syncthreads();
            if (threadIdx.x < 16) {
                u32 h = 0;
                for (int i = 0; i < NW; i++) h += whist[i][threadIdx.x];
                hist[threadIdx.x] = h;
            }
            __syncthreads();
            if (threadIdx.x == 0) {
                u32 accu = 0; int d = 15;
                for (; d > 0; d--) {
                    u32 h = hist[d];
                    if (accu + h >= (u32)rem) break;
                    accu += h;
                }
                sh_pval = pval | ((u32)d << shift);
                sh_rem = rem - (int)accu;
            }
            __syncthreads();
            pval = sh_pval; rem = sh_rem; pmask |= (0xFu << shift);
        }
    }

    float sgt = 0.f; u32 cgt = 0;
    if (k > 0) {
        for (int p = threadIdx.x; p < P; p += SEL_T) {
            u32 key = sk[p];
            if (key > pval) { sgt += __uint_as_float(key); cgt++; }
        }
    }
    for (int off = 32; off; off >>= 1) {
        sgt += __shfl_down(sgt, off);
        cgt += __shfl_down(cgt, off);
    }
    __syncthreads();
    if (lane == 0) { redf[w] = sgt; redu[w] = cgt; }
    __syncthreads();
    if (threadIdx.x == 0) {
        float s = 0.f; u32 c = 0;
        for (int i = 0; i < NW; i++) { s += redf[i]; c += redu[i]; }
        float t = __uint_as_float(pval);
        float lc_b = lcpos[b] + ((k > 0) ? (s + (float)(k - (int)c) * t) : 0.f);
        atomicAdd(&acc[0], (float)np);
        atomicAdd(&acc[1], loss_l[b]);
        atomicAdd(&acc[2], lc_b);
        __threadfence();
        u32 tk = atomicAdd(ticket, 1u);
        if (tk == (u32)(B - 1)) {
            float n  = atomicAdd(&acc[0], 0.f);   // coherent device-scope reads
            float ll = atomicAdd(&acc[1], 0.f);
            float lc = atomicAdd(&acc[2], 0.f);
            out[0] = ll / n;
            out[1] = lc / n;
        }
    }
}

// ---------------------------------------------------------------- launch

extern "C" void kernel_launch(void* const* d_in, const int* in_sizes, int n_in,
                              void* d_out, int out_size, void* d_ws, size_t ws_size,
                              hipStream_t stream) {
    const float* loc     = (const float*)d_in[0];
    const float* conf    = (const float*)d_in[1];
    const float* targets = (const float*)d_in[2];
    const float* priors  = (const float*)d_in[3];

    const int P = in_sizes[3] / 4;
    const int B = in_sizes[0] / (P * 4);
    const int O = in_sizes[2] / (B * 5);

    char* ws = (char*)d_ws;
    size_t off = 0;
    int*   num_pos = (int*)(ws + off);   off += (size_t)B * sizeof(int);
    float* loss_l  = (float*)(ws + off); off += (size_t)B * sizeof(float);
    float* lcpos   = (float*)(ws + off); off += (size_t)B * sizeof(float);
    float* acc     = (float*)(ws + off); off += 4 * sizeof(float);
    u32*   ticket  = (u32*)(ws + off);   off += sizeof(u32);
    const size_t zbytes = off;           // zero-init region (tbest excluded: plain-stored)
    off = (off + 15) & ~(size_t)15;
    ull*   tbest   = (ull*)(ws + off);   off += (size_t)B * O * sizeof(ull);
    float* F       = (float*)(ws + off); off += (size_t)B * P * sizeof(float); // bto
    int*   I       = (int*)(ws + off);   off += (size_t)B * P * sizeof(int);   // bti -> keys

    (void)hipMemsetAsync(d_ws, 0, zbytes, stream);

    const int SEG = 256 * PPT;
    const int S = (P + SEG - 1) / SEG;
    k_match<<<dim3(S, B), 256, 0, stream>>>(targets, priors, F, I, P, O, SEG);

    const int npairs = B * ((O + 1) / 2);
    k_tbest<<<(npairs + 3) / 4, 256, 0, stream>>>(targets, priors, tbest, P, O, npairs);

    const long long BP = (long long)B * P;
    k_fused<<<(int)((BP + CE_R - 1) / CE_R), 256, 0, stream>>>(
        conf, targets, priors, loc, tbest, F, I, num_pos, loss_l, lcpos, P, O, BP);

    k_select<<<B, SEL_T, (size_t)P * sizeof(u32), stream>>>(
        (const u32*)I, num_pos, loss_l, lcpos, acc, ticket, (float*)d_out, P, B);
}